// Round 2
// baseline (90.654 us; speedup 1.0000x reference)
//
#include <hip/hip_runtime.h>
#include <math.h>

#define BB 2048
#define DD 512
#define NS 7
#define KK 1024   // 2*DD concatenated GEMM K
#define BM 128
#define BN 64
#define BK 64
#define NT (KK / BK)  // 16 K-steps

typedef __attribute__((ext_vector_type(8))) short short8;
typedef __attribute__((ext_vector_type(4))) float floatx4;

typedef const __attribute__((address_space(1))) void gv_t;
typedef __attribute__((address_space(3))) void lv_t;
__device__ __forceinline__ void gl2lds16(const void* g, void* l) {
  __builtin_amdgcn_global_load_lds((gv_t*)g, (lv_t*)l, 16, 0, 0);
}

__device__ __forceinline__ unsigned short f2bf(float f) {
  unsigned int u = __float_as_uint(f);
  u += 0x7FFFu + ((u >> 16) & 1u);  // RNE
  return (unsigned short)(u >> 16);
}

// monotone float<->uint key for atomicMax over signed floats
__device__ __forceinline__ unsigned fkey(float f) {
  unsigned u = __float_as_uint(f);
  return (u & 0x80000000u) ? ~u : (u | 0x80000000u);
}
__device__ __forceinline__ float funkey(unsigned k) {
  unsigned u = (k & 0x80000000u) ? (k ^ 0x80000000u) : ~k;
  return __uint_as_float(u);
}

// chunk-XOR swizzle of the K index within each 64-col group, keyed by row&7.
// Producer (prep) writes swizzled; GEMM's linear global_load_lds staging then
// lands a swizzled LDS tile whose ds_read_b128 frag reads are conflict-minimal.
__device__ __forceinline__ int swz(int row, int c) {
  return (c & ~0x38) | ((((c >> 3) ^ row) & 7) << 3);
}

__device__ __forceinline__ float wave_reduce_sum(float v) {
#pragma unroll
  for (int off = 32; off > 0; off >>= 1) v += __shfl_down(v, off, 64);
  return v;
}
__device__ __forceinline__ float wave_reduce_max(float v) {
#pragma unroll
  for (int off = 32; off > 0; off >>= 1) v = fmaxf(v, __shfl_down(v, off, 64));
  return v;
}
__device__ __forceinline__ float block_reduce_sum256(float v, float* sbuf) {
  v = wave_reduce_sum(v);
  if ((threadIdx.x & 63) == 0) sbuf[threadIdx.x >> 6] = v;
  __syncthreads();
  float r = sbuf[0] + sbuf[1] + sbuf[2] + sbuf[3];
  __syncthreads();
  return r;
}
__device__ __forceinline__ float block_reduce_max256(float v, float* sbuf) {
  v = wave_reduce_max(v);
  if ((threadIdx.x & 63) == 0) sbuf[threadIdx.x >> 6] = v;
  __syncthreads();
  float r = fmaxf(fmaxf(sbuf[0], sbuf[1]), fmaxf(sbuf[2], sbuf[3]));
  __syncthreads();
  return r;
}

// ---------------------------------------------------------------------------
// Kernel 1 (merged prep): blocks [0,2048) = query rows, [2048,4096) = targets.
// Query:  Acat[q][0..511]=W=exp(-qls), Acat[q][512..1023]=-2*qm_n*W (swizzled),
//         qterm[q]=sum qm_n^2*W
// Target: Bcat[t][0..511]=S2=mean_s samp^2, [512..1023]=S1=mean_s samp (swz),
//         Mkey[t]=0 init; fin[0..1]=0 init (block 0).
__global__ __launch_bounds__(256) void prep(
    const float* __restrict__ qmean, const float* __restrict__ qls,
    const float* __restrict__ tmean, const float* __restrict__ tls,
    const float* __restrict__ eps,
    unsigned short* __restrict__ Acat, unsigned short* __restrict__ Bcat,
    float* __restrict__ qterm, unsigned* __restrict__ Mkey,
    unsigned long long* __restrict__ fin) {
  __shared__ float sbuf[4];
  const int b = blockIdx.x, tid = threadIdx.x;
  if (b < BB) {
    const int q = b;
    if (q == 0 && tid < 2) fin[tid] = 0ull;
    const float* xm = qmean + q * DD;
    const float* xl = qls + q * DD;
    float x0 = xm[tid], x1 = xm[tid + 256];
    float ss = block_reduce_sum256(x0 * x0 + x1 * x1, sbuf);
    float inv = 1.0f / fmaxf(sqrtf(ss), 1e-12f);
    float w0 = expf(-xl[tid]), w1 = expf(-xl[tid + 256]);
    float n0 = x0 * inv, n1 = x1 * inv;
    unsigned short* arow = Acat + q * KK;
    arow[swz(q, tid)]            = f2bf(w0);
    arow[swz(q, tid + 256)]      = f2bf(w1);
    arow[swz(q, DD + tid)]       = f2bf(-2.0f * n0 * w0);
    arow[swz(q, DD + tid + 256)] = f2bf(-2.0f * n1 * w1);
    float qt = block_reduce_sum256(n0 * n0 * w0 + n1 * n1 * w1, sbuf);
    if (tid == 0) qterm[q] = qt;
  } else {
    const int t = b - BB;
    if (tid == 0) Mkey[t] = 0u;  // < fkey of any finite float
    const float* xm = tmean + t * DD;
    const float* xl = tls + t * DD;
    float x0 = xm[tid], x1 = xm[tid + 256];
    float ss = block_reduce_sum256(x0 * x0 + x1 * x1, sbuf);
    float inv = 1.0f / fmaxf(sqrtf(ss), 1e-12f);
    unsigned short* brow = Bcat + t * KK;
    const float i7 = 1.0f / 7.0f;
#pragma unroll
    for (int h = 0; h < 2; ++h) {
      int d = tid + h * 256;
      float tm = (h ? x1 : x0) * inv;
      float sig = expf(xl[d]);
      float se = 0.f, se2 = 0.f;
#pragma unroll
      for (int s = 0; s < NS; ++s) {
        float e = eps[(t * NS + s) * DD + d];
        se += e;
        se2 += e * e;
      }
      float s1 = tm + sig * se * i7;
      float s2 = tm * tm + 2.0f * tm * sig * se * i7 + sig * sig * se2 * i7;
      brow[swz(t, d)]      = f2bf(s2);
      brow[swz(t, DD + d)] = f2bf(s1);
    }
  }
}

// ---------------------------------------------------------------------------
// Kernel 2: loc[q][t] = -0.5*(sum_k Acat[q,k]*Bcat[t,k] + qterm[q])
// 128x64 tile, grid (32,16)=512 blocks (2 blocks/CU), 4 waves (2x2), BK=64,
// double-buffered LDS filled via global_load_lds dwordx4. Column max fused
// into epilogue via atomicMax on encoded keys.
__global__ __launch_bounds__(256) void gemm_loc(
    const unsigned short* __restrict__ Acat,
    const unsigned short* __restrict__ Bcat,
    const float* __restrict__ qterm,
    float* __restrict__ loc, unsigned* __restrict__ Mkey) {
  __shared__ short As[2][BM * BK];  // 2 x 16 KB
  __shared__ short Bs[2][BN * BK];  // 2 x  8 KB
  const int tid = threadIdx.x, lane = tid & 63, wid = tid >> 6;
  const int brow = blockIdx.y * BM, bcol = blockIdx.x * BN;
  const int wr = wid >> 1, wc = wid & 1;          // wave 64x32 sub-tile
  const int fr = lane & 15, kg = lane >> 4, f7 = fr & 7;
  const int srow = lane >> 3, scol = (lane & 7) * 8;

  floatx4 acc[4][2];
#pragma unroll
  for (int m = 0; m < 4; ++m)
#pragma unroll
    for (int n = 0; n < 2; ++n) acc[m][n] = (floatx4){0.f, 0.f, 0.f, 0.f};

  const unsigned short* gA = Acat + (size_t)(brow + wid * 32 + srow) * KK + scol;
  const unsigned short* gB = Bcat + (size_t)(bcol + wid * 16 + srow) * KK + scol;

  // prologue: stage K-tile 0 into buffer 0
  {
    short* la = &As[0][wid * 2048];
    short* lb = &Bs[0][wid * 1024];
#pragma unroll
    for (int j = 0; j < 4; ++j) gl2lds16(gA + (size_t)j * 8 * KK, la + j * 512);
#pragma unroll
    for (int j = 0; j < 2; ++j) gl2lds16(gB + (size_t)j * 8 * KK, lb + j * 512);
  }

  for (int kt = 0; kt < NT; ++kt) {
    __syncthreads();  // drains vmcnt(0): buffer (kt&1) staged & prior reads done
    const int cur = kt & 1;
    if (kt + 1 < NT) {
      const int kc = (kt + 1) * BK;
      short* la = &As[cur ^ 1][wid * 2048];
      short* lb = &Bs[cur ^ 1][wid * 1024];
#pragma unroll
      for (int j = 0; j < 4; ++j)
        gl2lds16(gA + (size_t)j * 8 * KK + kc, la + j * 512);
#pragma unroll
      for (int j = 0; j < 2; ++j)
        gl2lds16(gB + (size_t)j * 8 * KK + kc, lb + j * 512);
    }
    const short* a = As[cur];
    const short* bp = Bs[cur];
#pragma unroll
    for (int kh = 0; kh < 2; ++kh) {
      const int co = (((kh * 4 + kg) ^ f7) << 3);  // un-swizzle chunk
      short8 af[4], bf[2];
#pragma unroll
      for (int m = 0; m < 4; ++m)
        af[m] = *reinterpret_cast<const short8*>(&a[(wr * 64 + m * 16 + fr) * BK + co]);
#pragma unroll
      for (int n = 0; n < 2; ++n)
        bf[n] = *reinterpret_cast<const short8*>(&bp[(wc * 32 + n * 16 + fr) * BK + co]);
#pragma unroll
      for (int m = 0; m < 4; ++m)
#pragma unroll
        for (int n = 0; n < 2; ++n)
          acc[m][n] = __builtin_amdgcn_mfma_f32_16x16x32_bf16(af[m], bf[n],
                                                              acc[m][n], 0, 0, 0);
    }
  }

  // epilogue: C row = 4*kg + r4 (+m*16 + wr*64), col = fr (+n*16 + wc*32)
#pragma unroll
  for (int n = 0; n < 2; ++n) {
    const int col = bcol + wc * 32 + n * 16 + fr;
    float cm = -3.402823466e38f;
#pragma unroll
    for (int m = 0; m < 4; ++m) {
      const int row = brow + wr * 64 + m * 16 + kg * 4;
#pragma unroll
      for (int r4 = 0; r4 < 4; ++r4) {
        float v = -0.5f * (acc[m][n][r4] + qterm[row + r4]);
        loc[(size_t)(row + r4) * BB + col] = v;
        cm = fmaxf(cm, v);
      }
    }
    cm = fmaxf(cm, __shfl_xor(cm, 16, 64));
    cm = fmaxf(cm, __shfl_xor(cm, 32, 64));
    if (kg == 0) atomicMax(&Mkey[col], fkey(cm));  // order-invariant
  }
}

// ---------------------------------------------------------------------------
// Kernel 3: per-row LSE + diag; deterministic fixed-point atomic accumulation
// of the mean; last block writes the loss.
__global__ __launch_bounds__(256) void row_lse(
    const float* __restrict__ loc, const unsigned* __restrict__ Mkey,
    unsigned long long* __restrict__ fin, float* __restrict__ out) {
  __shared__ float sbuf[4];
  __shared__ float lg[BB];
  const int q = blockIdx.x, tid = threadIdx.x;
  float m = -3.402823466e38f;
#pragma unroll
  for (int i = 0; i < 8; ++i) {
    int t = tid + i * 256;
    float x = loc[(size_t)q * BB + t] - funkey(Mkey[t]);
    lg[t] = x;
    m = fmaxf(m, x);
  }
  m = block_reduce_max256(m, sbuf);  // barrier => lg[] visible
  float s = 0.f;
#pragma unroll
  for (int i = 0; i < 8; ++i) s += expf(lg[tid + i * 256] - m);
  s = block_reduce_sum256(s, sbuf);
  if (tid == 0) {
    float rv = lg[q] - (m + logf(s));
    long long contrib = (long long)((double)rv * 1048576.0);
    atomicAdd(&fin[0], (unsigned long long)contrib);  // integer: order-invariant
    __threadfence();
    unsigned long long done = atomicAdd(&fin[1], 1ull);
    if (done == (unsigned long long)(BB - 1)) {
      unsigned long long total = atomicAdd(&fin[0], 0ull);
      out[0] = (float)(-((double)(long long)total) / (1048576.0 * (double)BB));
    }
  }
}

// ---------------------------------------------------------------------------
extern "C" void kernel_launch(void* const* d_in, const int* in_sizes, int n_in,
                              void* d_out, int out_size, void* d_ws, size_t ws_size,
                              hipStream_t stream) {
  const float* qmean = (const float*)d_in[0];
  const float* qls   = (const float*)d_in[1];
  // d_in[2] query_z: cancels (broadcasts on target axis -> drops in colmax+softmax)
  const float* tmean = (const float*)d_in[3];
  const float* tls   = (const float*)d_in[4];
  // d_in[5] target_z: unused by reference
  const float* eps   = (const float*)d_in[6];

  char* ws = (char*)d_ws;
  unsigned short* Acat = (unsigned short*)(ws + 0);                  // 4 MB
  unsigned short* Bcat = (unsigned short*)(ws + (4u << 20));         // 4 MB
  float* qterm         = (float*)(ws + (8u << 20));                  // 8 KB
  unsigned* Mkey       = (unsigned*)(ws + (8u << 20) + 8192);        // 8 KB
  unsigned long long* fin = (unsigned long long*)(ws + (8u << 20) + 16384);  // 16 B
  float* loc           = (float*)(ws + (8u << 20) + 65536);          // 16 MB

  prep<<<2 * BB, 256, 0, stream>>>(qmean, qls, tmean, tls, eps,
                                   Acat, Bcat, qterm, Mkey, fin);
  gemm_loc<<<dim3(BB / BN, BB / BM), 256, 0, stream>>>(Acat, Bcat, qterm, loc, Mkey);
  row_lse<<<BB, 256, 0, stream>>>(loc, Mkey, fin, (float*)d_out);
}

// Round 3
// 41.974 us; speedup vs baseline: 2.1597x; 2.1597x over previous
//
#include <hip/hip_runtime.h>
#include <math.h>

#define BB 2048
#define DD 512
#define NS 7
#define KK 1024   // 2*DD concatenated GEMM K
#define BM 128
#define BN 64
#define BK 64
#define NT (KK / BK)  // 16 K-steps

typedef __attribute__((ext_vector_type(8))) short short8;
typedef __attribute__((ext_vector_type(4))) float floatx4;

typedef const __attribute__((address_space(1))) void gv_t;
typedef __attribute__((address_space(3))) void lv_t;
__device__ __forceinline__ void gl2lds16(const void* g, void* l) {
  __builtin_amdgcn_global_load_lds((gv_t*)g, (lv_t*)l, 16, 0, 0);
}

__device__ __forceinline__ unsigned short f2bf(float f) {
  unsigned int u = __float_as_uint(f);
  u += 0x7FFFu + ((u >> 16) & 1u);  // RNE
  return (unsigned short)(u >> 16);
}

// monotone float<->uint key for atomicMax over signed floats
__device__ __forceinline__ unsigned fkey(float f) {
  unsigned u = __float_as_uint(f);
  return (u & 0x80000000u) ? ~u : (u | 0x80000000u);
}
__device__ __forceinline__ float funkey(unsigned k) {
  unsigned u = (k & 0x80000000u) ? (k ^ 0x80000000u) : ~k;
  return __uint_as_float(u);
}

// chunk-XOR swizzle of the K index within each 64-col group, keyed by row&7.
// Producer (prep) writes swizzled; GEMM's linear global_load_lds staging then
// lands a swizzled LDS tile whose ds_read_b128 frag reads are conflict-minimal.
__device__ __forceinline__ int swz(int row, int c) {
  return (c & ~0x38) | ((((c >> 3) ^ row) & 7) << 3);
}

__device__ __forceinline__ float wave_reduce_sum(float v) {
#pragma unroll
  for (int off = 32; off > 0; off >>= 1) v += __shfl_down(v, off, 64);
  return v;
}
__device__ __forceinline__ float wave_reduce_max(float v) {
#pragma unroll
  for (int off = 32; off > 0; off >>= 1) v = fmaxf(v, __shfl_down(v, off, 64));
  return v;
}
__device__ __forceinline__ float block_reduce_sum256(float v, float* sbuf) {
  v = wave_reduce_sum(v);
  if ((threadIdx.x & 63) == 0) sbuf[threadIdx.x >> 6] = v;
  __syncthreads();
  float r = sbuf[0] + sbuf[1] + sbuf[2] + sbuf[3];
  __syncthreads();
  return r;
}
__device__ __forceinline__ float block_reduce_max256(float v, float* sbuf) {
  v = wave_reduce_max(v);
  if ((threadIdx.x & 63) == 0) sbuf[threadIdx.x >> 6] = v;
  __syncthreads();
  float r = fmaxf(fmaxf(sbuf[0], sbuf[1]), fmaxf(sbuf[2], sbuf[3]));
  __syncthreads();
  return r;
}

// ---------------------------------------------------------------------------
// Kernel 1 (merged prep): blocks [0,2048) = query rows, [2048,4096) = targets.
__global__ __launch_bounds__(256) void prep(
    const float* __restrict__ qmean, const float* __restrict__ qls,
    const float* __restrict__ tmean, const float* __restrict__ tls,
    const float* __restrict__ eps,
    unsigned short* __restrict__ Acat, unsigned short* __restrict__ Bcat,
    float* __restrict__ qterm, unsigned* __restrict__ Mkey) {
  __shared__ float sbuf[4];
  const int b = blockIdx.x, tid = threadIdx.x;
  if (b < BB) {
    const int q = b;
    const float* xm = qmean + q * DD;
    const float* xl = qls + q * DD;
    float x0 = xm[tid], x1 = xm[tid + 256];
    float ss = block_reduce_sum256(x0 * x0 + x1 * x1, sbuf);
    float inv = 1.0f / fmaxf(sqrtf(ss), 1e-12f);
    float w0 = expf(-xl[tid]), w1 = expf(-xl[tid + 256]);
    float n0 = x0 * inv, n1 = x1 * inv;
    unsigned short* arow = Acat + q * KK;
    arow[swz(q, tid)]            = f2bf(w0);
    arow[swz(q, tid + 256)]      = f2bf(w1);
    arow[swz(q, DD + tid)]       = f2bf(-2.0f * n0 * w0);
    arow[swz(q, DD + tid + 256)] = f2bf(-2.0f * n1 * w1);
    float qt = block_reduce_sum256(n0 * n0 * w0 + n1 * n1 * w1, sbuf);
    if (tid == 0) qterm[q] = qt;
  } else {
    const int t = b - BB;
    if (tid == 0) Mkey[t] = 0u;  // < fkey of any finite float
    const float* xm = tmean + t * DD;
    const float* xl = tls + t * DD;
    float x0 = xm[tid], x1 = xm[tid + 256];
    float ss = block_reduce_sum256(x0 * x0 + x1 * x1, sbuf);
    float inv = 1.0f / fmaxf(sqrtf(ss), 1e-12f);
    unsigned short* brow = Bcat + t * KK;
    const float i7 = 1.0f / 7.0f;
#pragma unroll
    for (int h = 0; h < 2; ++h) {
      int d = tid + h * 256;
      float tm = (h ? x1 : x0) * inv;
      float sig = expf(xl[d]);
      float se = 0.f, se2 = 0.f;
#pragma unroll
      for (int s = 0; s < NS; ++s) {
        float e = eps[(t * NS + s) * DD + d];
        se += e;
        se2 += e * e;
      }
      float s1 = tm + sig * se * i7;
      float s2 = tm * tm + 2.0f * tm * sig * se * i7 + sig * sig * se2 * i7;
      brow[swz(t, d)]      = f2bf(s2);
      brow[swz(t, DD + d)] = f2bf(s1);
    }
  }
}

// ---------------------------------------------------------------------------
// Kernel 2: loc[q][t] = -0.5*(sum_k Acat[q,k]*Bcat[t,k] + qterm[q])
// 128x64 tile, grid (32,16)=512 blocks (2/CU), 4 waves (2x2), BK=64,
// double-buffered LDS via global_load_lds dwordx4. Column max fused into the
// epilogue via atomicMax on encoded keys (2048 distinct addresses -> pipelined).
__global__ __launch_bounds__(256) void gemm_loc(
    const unsigned short* __restrict__ Acat,
    const unsigned short* __restrict__ Bcat,
    const float* __restrict__ qterm,
    float* __restrict__ loc, unsigned* __restrict__ Mkey) {
  __shared__ short As[2][BM * BK];  // 2 x 16 KB
  __shared__ short Bs[2][BN * BK];  // 2 x  8 KB
  const int tid = threadIdx.x, lane = tid & 63, wid = tid >> 6;
  const int brow = blockIdx.y * BM, bcol = blockIdx.x * BN;
  const int wr = wid >> 1, wc = wid & 1;          // wave 64x32 sub-tile
  const int fr = lane & 15, kg = lane >> 4, f7 = fr & 7;
  const int srow = lane >> 3, scol = (lane & 7) * 8;

  floatx4 acc[4][2];
#pragma unroll
  for (int m = 0; m < 4; ++m)
#pragma unroll
    for (int n = 0; n < 2; ++n) acc[m][n] = (floatx4){0.f, 0.f, 0.f, 0.f};

  const unsigned short* gA = Acat + (size_t)(brow + wid * 32 + srow) * KK + scol;
  const unsigned short* gB = Bcat + (size_t)(bcol + wid * 16 + srow) * KK + scol;

  // prologue: stage K-tile 0 into buffer 0
  {
    short* la = &As[0][wid * 2048];
    short* lb = &Bs[0][wid * 1024];
#pragma unroll
    for (int j = 0; j < 4; ++j) gl2lds16(gA + (size_t)j * 8 * KK, la + j * 512);
#pragma unroll
    for (int j = 0; j < 2; ++j) gl2lds16(gB + (size_t)j * 8 * KK, lb + j * 512);
  }

  for (int kt = 0; kt < NT; ++kt) {
    __syncthreads();  // drains vmcnt(0): buffer (kt&1) staged & prior reads done
    const int cur = kt & 1;
    if (kt + 1 < NT) {
      const int kc = (kt + 1) * BK;
      short* la = &As[cur ^ 1][wid * 2048];
      short* lb = &Bs[cur ^ 1][wid * 1024];
#pragma unroll
      for (int j = 0; j < 4; ++j)
        gl2lds16(gA + (size_t)j * 8 * KK + kc, la + j * 512);
#pragma unroll
      for (int j = 0; j < 2; ++j)
        gl2lds16(gB + (size_t)j * 8 * KK + kc, lb + j * 512);
    }
    const short* a = As[cur];
    const short* bp = Bs[cur];
#pragma unroll
    for (int kh = 0; kh < 2; ++kh) {
      const int co = (((kh * 4 + kg) ^ f7) << 3);  // un-swizzle chunk
      short8 af[4], bf[2];
#pragma unroll
      for (int m = 0; m < 4; ++m)
        af[m] = *reinterpret_cast<const short8*>(&a[(wr * 64 + m * 16 + fr) * BK + co]);
#pragma unroll
      for (int n = 0; n < 2; ++n)
        bf[n] = *reinterpret_cast<const short8*>(&bp[(wc * 32 + n * 16 + fr) * BK + co]);
#pragma unroll
      for (int m = 0; m < 4; ++m)
#pragma unroll
        for (int n = 0; n < 2; ++n)
          acc[m][n] = __builtin_amdgcn_mfma_f32_16x16x32_bf16(af[m], bf[n],
                                                              acc[m][n], 0, 0, 0);
    }
  }

  // epilogue: C row = 4*kg + r4 (+m*16 + wr*64), col = fr (+n*16 + wc*32)
#pragma unroll
  for (int n = 0; n < 2; ++n) {
    const int col = bcol + wc * 32 + n * 16 + fr;
    float cm = -3.402823466e38f;
#pragma unroll
    for (int m = 0; m < 4; ++m) {
      const int row = brow + wr * 64 + m * 16 + kg * 4;
#pragma unroll
      for (int r4 = 0; r4 < 4; ++r4) {
        float v = -0.5f * (acc[m][n][r4] + qterm[row + r4]);
        loc[(size_t)(row + r4) * BB + col] = v;
        cm = fmaxf(cm, v);
      }
    }
    cm = fmaxf(cm, __shfl_xor(cm, 16, 64));
    cm = fmaxf(cm, __shfl_xor(cm, 32, 64));
    if (kg == 0) atomicMax(&Mkey[col], fkey(cm));  // order-invariant
  }
}

// ---------------------------------------------------------------------------
// Kernel 3: per-row LSE + diag -> rowval[q]. No global atomics (round-2 lesson:
// 2048 blocks x 2 same-address atomics serialized into 58us).
__global__ __launch_bounds__(256) void row_lse(
    const float* __restrict__ loc, const unsigned* __restrict__ Mkey,
    float* __restrict__ rowval) {
  __shared__ float sbuf[4];
  __shared__ float lg[BB];
  const int q = blockIdx.x, tid = threadIdx.x;
  float m = -3.402823466e38f;
#pragma unroll
  for (int i = 0; i < 8; ++i) {
    int t = tid + i * 256;
    float x = loc[(size_t)q * BB + t] - funkey(Mkey[t]);
    lg[t] = x;
    m = fmaxf(m, x);
  }
  m = block_reduce_max256(m, sbuf);  // barrier => lg[] visible
  float s = 0.f;
#pragma unroll
  for (int i = 0; i < 8; ++i) s += expf(lg[tid + i * 256] - m);
  s = block_reduce_sum256(s, sbuf);
  if (tid == 0) rowval[q] = lg[q] - (m + logf(s));
}

// ---------------------------------------------------------------------------
// Kernel 4: loss = -mean_q rowval[q]  (single block)
__global__ __launch_bounds__(256) void final_loss(
    const float* __restrict__ rowval, float* __restrict__ out) {
  __shared__ float sbuf[4];
  const int tid = threadIdx.x;
  float s = 0.f;
#pragma unroll
  for (int i = 0; i < 8; ++i) s += rowval[tid + i * 256];
  s = block_reduce_sum256(s, sbuf);
  if (tid == 0) out[0] = -s * (1.0f / (float)BB);
}

// ---------------------------------------------------------------------------
extern "C" void kernel_launch(void* const* d_in, const int* in_sizes, int n_in,
                              void* d_out, int out_size, void* d_ws, size_t ws_size,
                              hipStream_t stream) {
  const float* qmean = (const float*)d_in[0];
  const float* qls   = (const float*)d_in[1];
  // d_in[2] query_z: cancels (broadcasts on target axis -> drops in colmax+softmax)
  const float* tmean = (const float*)d_in[3];
  const float* tls   = (const float*)d_in[4];
  // d_in[5] target_z: unused by reference
  const float* eps   = (const float*)d_in[6];

  char* ws = (char*)d_ws;
  unsigned short* Acat = (unsigned short*)(ws + 0);                  // 4 MB
  unsigned short* Bcat = (unsigned short*)(ws + (4u << 20));         // 4 MB
  float* qterm         = (float*)(ws + (8u << 20));                  // 8 KB
  unsigned* Mkey       = (unsigned*)(ws + (8u << 20) + 8192);        // 8 KB
  float* rowval        = (float*)(ws + (8u << 20) + 16384);          // 8 KB
  float* loc           = (float*)(ws + (8u << 20) + 65536);          // 16 MB

  prep<<<2 * BB, 256, 0, stream>>>(qmean, qls, tmean, tls, eps,
                                   Acat, Bcat, qterm, Mkey);
  gemm_loc<<<dim3(BB / BN, BB / BM), 256, 0, stream>>>(Acat, Bcat, qterm, loc, Mkey);
  row_lse<<<BB, 256, 0, stream>>>(loc, Mkey, rowval);
  final_loss<<<1, 256, 0, stream>>>(rowval, (float*)d_out);
}

// Round 4
// 39.539 us; speedup vs baseline: 2.2928x; 1.0616x over previous
//
#include <hip/hip_runtime.h>
#include <math.h>

#define BB 2048
#define DD 512
#define NS 7
#define KK 1024   // 2*DD concatenated GEMM K
#define BM 128
#define BN 64
#define BK 64
#define NT (KK / BK)  // 16 K-steps

typedef __attribute__((ext_vector_type(8))) short short8;
typedef __attribute__((ext_vector_type(4))) float floatx4;

typedef const __attribute__((address_space(1))) void gv_t;
typedef __attribute__((address_space(3))) void lv_t;
__device__ __forceinline__ void gl2lds16(const void* g, void* l) {
  __builtin_amdgcn_global_load_lds((gv_t*)g, (lv_t*)l, 16, 0, 0);
}

__device__ __forceinline__ unsigned short f2bf(float f) {
  unsigned int u = __float_as_uint(f);
  u += 0x7FFFu + ((u >> 16) & 1u);  // RNE
  return (unsigned short)(u >> 16);
}
__device__ __forceinline__ float bf2f(unsigned short u) {
  return __uint_as_float(((unsigned)u) << 16);
}

// monotone float<->uint key for atomicMax over signed floats
__device__ __forceinline__ unsigned fkey(float f) {
  unsigned u = __float_as_uint(f);
  return (u & 0x80000000u) ? ~u : (u | 0x80000000u);
}
__device__ __forceinline__ float funkey(unsigned k) {
  unsigned u = (k & 0x80000000u) ? (k ^ 0x80000000u) : ~k;
  return __uint_as_float(u);
}

// chunk-XOR swizzle of the K index within each 64-col group, keyed by row&7.
// Producer (prep) writes swizzled; GEMM's linear global_load_lds staging then
// lands a swizzled LDS tile whose ds_read_b128 frag reads are conflict-minimal.
__device__ __forceinline__ int swz(int row, int c) {
  return (c & ~0x38) | ((((c >> 3) ^ row) & 7) << 3);
}

__device__ __forceinline__ float wave_reduce_sum(float v) {
#pragma unroll
  for (int off = 32; off > 0; off >>= 1) v += __shfl_down(v, off, 64);
  return v;
}
__device__ __forceinline__ float wave_reduce_max(float v) {
#pragma unroll
  for (int off = 32; off > 0; off >>= 1) v = fmaxf(v, __shfl_down(v, off, 64));
  return v;
}
__device__ __forceinline__ float block_reduce_sum256(float v, float* sbuf) {
  v = wave_reduce_sum(v);
  if ((threadIdx.x & 63) == 0) sbuf[threadIdx.x >> 6] = v;
  __syncthreads();
  float r = sbuf[0] + sbuf[1] + sbuf[2] + sbuf[3];
  __syncthreads();
  return r;
}
__device__ __forceinline__ float block_reduce_max256(float v, float* sbuf) {
  v = wave_reduce_max(v);
  if ((threadIdx.x & 63) == 0) sbuf[threadIdx.x >> 6] = v;
  __syncthreads();
  float r = fmaxf(fmaxf(sbuf[0], sbuf[1]), fmaxf(sbuf[2], sbuf[3]));
  __syncthreads();
  return r;
}

// ---------------------------------------------------------------------------
// Kernel 1 (merged prep): blocks [0,2048) = query rows, [2048,4096) = targets.
// float2 loads (8B/lane) per G13.
__global__ __launch_bounds__(256) void prep(
    const float* __restrict__ qmean, const float* __restrict__ qls,
    const float* __restrict__ tmean, const float* __restrict__ tls,
    const float* __restrict__ eps,
    unsigned short* __restrict__ Acat, unsigned short* __restrict__ Bcat,
    float* __restrict__ qterm, unsigned* __restrict__ Mkey) {
  __shared__ float sbuf[4];
  const int b = blockIdx.x, tid = threadIdx.x;
  const int c0 = 2 * tid;
  if (b < BB) {
    const int q = b;
    float2 x = ((const float2*)(qmean + (size_t)q * DD))[tid];
    float2 l = ((const float2*)(qls + (size_t)q * DD))[tid];
    float ss = block_reduce_sum256(x.x * x.x + x.y * x.y, sbuf);
    float inv = 1.0f / fmaxf(sqrtf(ss), 1e-12f);
    float w0 = expf(-l.x), w1 = expf(-l.y);
    float n0 = x.x * inv, n1 = x.y * inv;
    unsigned short* arow = Acat + (size_t)q * KK;
    ushort2 wp, np;
    wp.x = f2bf(w0);             wp.y = f2bf(w1);
    np.x = f2bf(-2.0f * n0 * w0); np.y = f2bf(-2.0f * n1 * w1);
    *(ushort2*)&arow[swz(q, c0)]      = wp;
    *(ushort2*)&arow[swz(q, DD + c0)] = np;
    float qt = block_reduce_sum256(n0 * n0 * w0 + n1 * n1 * w1, sbuf);
    if (tid == 0) qterm[q] = qt;
  } else {
    const int t = b - BB;
    if (tid == 0) Mkey[t] = 0u;  // < fkey of any finite float
    float2 x = ((const float2*)(tmean + (size_t)t * DD))[tid];
    float2 l = ((const float2*)(tls + (size_t)t * DD))[tid];
    float ss = block_reduce_sum256(x.x * x.x + x.y * x.y, sbuf);
    float inv = 1.0f / fmaxf(sqrtf(ss), 1e-12f);
    float tm0 = x.x * inv, tm1 = x.y * inv;
    float sg0 = expf(l.x), sg1 = expf(l.y);
    float se0 = 0.f, sq0 = 0.f, se1 = 0.f, sq1 = 0.f;
    const float2* ep = (const float2*)(eps + (size_t)t * NS * DD);
#pragma unroll
    for (int s = 0; s < NS; ++s) {
      float2 e = ep[s * (DD / 2) + tid];
      se0 += e.x; sq0 += e.x * e.x;
      se1 += e.y; sq1 += e.y * e.y;
    }
    const float i7 = 1.0f / 7.0f;
    float m0 = sg0 * se0 * i7, m1 = sg1 * se1 * i7;
    unsigned short* brow = Bcat + (size_t)t * KK;
    ushort2 s2p, s1p;
    s2p.x = f2bf(tm0 * tm0 + 2.0f * tm0 * m0 + sg0 * sg0 * sq0 * i7);
    s2p.y = f2bf(tm1 * tm1 + 2.0f * tm1 * m1 + sg1 * sg1 * sq1 * i7);
    s1p.x = f2bf(tm0 + m0); s1p.y = f2bf(tm1 + m1);
    *(ushort2*)&brow[swz(t, c0)]      = s2p;
    *(ushort2*)&brow[swz(t, DD + c0)] = s1p;
  }
}

// ---------------------------------------------------------------------------
// Kernel 2: loc[q][t] = -0.5*(sum_k Acat[q,k]*Bcat[t,k] + qterm[q]) in bf16.
// 128x64 tile, grid 512 (2 blocks/CU), 4 waves. Triple-buffered LDS via
// global_load_lds dwordx4; raw s_barrier + counted vmcnt(6) (T3/T4-lite:
// never drain vmcnt to 0 in the main loop). Column max fused via atomicMax
// on 2048 distinct encoded keys. XCD-bijective block swizzle (T1).
__global__ __launch_bounds__(256) void gemm_loc(
    const unsigned short* __restrict__ Acat,
    const unsigned short* __restrict__ Bcat,
    const float* __restrict__ qterm,
    unsigned short* __restrict__ loc, unsigned* __restrict__ Mkey) {
  __shared__ short As[3][BM * BK];  // 3 x 16 KB
  __shared__ short Bs[3][BN * BK];  // 3 x  8 KB
  const int tid = threadIdx.x, lane = tid & 63, wid = tid >> 6;
  // XCD-aware bijective remap: 512 blocks, 8 XCDs, 64 contiguous tiles each.
  const int lin = blockIdx.y * (BB / BN) + blockIdx.x;       // hw dispatch id
  const int id2 = (lin & 7) * 64 + (lin >> 3);               // bijective (512%8==0)
  const int brow = (id2 >> 5) * BM, bcol = (id2 & 31) * BN;
  const int wr = wid >> 1, wc = wid & 1;          // wave 64x32 sub-tile
  const int fr = lane & 15, kg = lane >> 4, f7 = fr & 7;
  const int srow = lane >> 3, scol = (lane & 7) * 8;

  floatx4 acc[4][2];
#pragma unroll
  for (int m = 0; m < 4; ++m)
#pragma unroll
    for (int n = 0; n < 2; ++n) acc[m][n] = (floatx4){0.f, 0.f, 0.f, 0.f};

  const unsigned short* gA = Acat + (size_t)(brow + wid * 32 + srow) * KK + scol;
  const unsigned short* gB = Bcat + (size_t)(bcol + wid * 16 + srow) * KK + scol;

  // prologue: stage K-tiles 0,1 into buffers 0,1 (12 loads in flight / wave)
#pragma unroll
  for (int p = 0; p < 2; ++p) {
    short* la = &As[p][wid * 2048];
    short* lb = &Bs[p][wid * 1024];
#pragma unroll
    for (int j = 0; j < 4; ++j) gl2lds16(gA + (size_t)j * 8 * KK + p * BK, la + j * 512);
#pragma unroll
    for (int j = 0; j < 2; ++j) gl2lds16(gB + (size_t)j * 8 * KK + p * BK, lb + j * 512);
  }

#pragma unroll
  for (int kt = 0; kt < NT; ++kt) {
    // own tile-kt loads complete (vmcnt in-order); tile kt+1 may stay in flight
    if (kt < NT - 1) asm volatile("s_waitcnt vmcnt(6)" ::: "memory");
    else             asm volatile("s_waitcnt vmcnt(0)" ::: "memory");
    __builtin_amdgcn_s_barrier();  // all waves' tile-kt data now in LDS
    if (kt + 2 < NT) {
      // overwrite buf[(kt-1)%3]: all waves finished kt-1 reads before barrier
      const int kc = (kt + 2) * BK, nb = (kt + 2) % 3;
      short* la = &As[nb][wid * 2048];
      short* lb = &Bs[nb][wid * 1024];
#pragma unroll
      for (int j = 0; j < 4; ++j) gl2lds16(gA + (size_t)j * 8 * KK + kc, la + j * 512);
#pragma unroll
      for (int j = 0; j < 2; ++j) gl2lds16(gB + (size_t)j * 8 * KK + kc, lb + j * 512);
    }
    const short* a  = As[kt % 3];
    const short* bp = Bs[kt % 3];
#pragma unroll
    for (int kh = 0; kh < 2; ++kh) {
      const int co = (((kh * 4 + kg) ^ f7) << 3);  // un-swizzle chunk
      short8 af[4], bf[2];
#pragma unroll
      for (int m = 0; m < 4; ++m)
        af[m] = *reinterpret_cast<const short8*>(&a[(wr * 64 + m * 16 + fr) * BK + co]);
#pragma unroll
      for (int n = 0; n < 2; ++n)
        bf[n] = *reinterpret_cast<const short8*>(&bp[(wc * 32 + n * 16 + fr) * BK + co]);
#pragma unroll
      for (int m = 0; m < 4; ++m)
#pragma unroll
        for (int n = 0; n < 2; ++n)
          acc[m][n] = __builtin_amdgcn_mfma_f32_16x16x32_bf16(af[m], bf[n],
                                                              acc[m][n], 0, 0, 0);
    }
  }

  // epilogue: C row = 4*kg + r4 (+m*16 + wr*64), col = fr (+n*16 + wc*32)
#pragma unroll
  for (int n = 0; n < 2; ++n) {
    const int col = bcol + wc * 32 + n * 16 + fr;
    float cm = -3.402823466e38f;
#pragma unroll
    for (int m = 0; m < 4; ++m) {
      const int row = brow + wr * 64 + m * 16 + kg * 4;
#pragma unroll
      for (int r4 = 0; r4 < 4; ++r4) {
        float v = -0.5f * (acc[m][n][r4] + qterm[row + r4]);
        loc[(size_t)(row + r4) * BB + col] = f2bf(v);
        cm = fmaxf(cm, v);
      }
    }
    cm = fmaxf(cm, __shfl_xor(cm, 16, 64));
    cm = fmaxf(cm, __shfl_xor(cm, 32, 64));
    if (kg == 0) atomicMax(&Mkey[col], fkey(cm));  // order-invariant
  }
}

// ---------------------------------------------------------------------------
// Kernel 3: per-row LSE + diag -> rowval[q]. Single pass, all in registers;
// no global atomics (round-2 lesson: same-address atomics serialize).
__global__ __launch_bounds__(256) void row_lse(
    const unsigned short* __restrict__ loc, const unsigned* __restrict__ Mkey,
    float* __restrict__ rowval) {
  __shared__ float sbuf[4];
  __shared__ float sdiag;
  const int q = blockIdx.x, tid = threadIdx.x;
  short8 v = ((const short8*)(loc + (size_t)q * BB))[tid];  // t = 8tid..8tid+7
  uint4 k0 = ((const uint4*)Mkey)[2 * tid];
  uint4 k1 = ((const uint4*)Mkey)[2 * tid + 1];
  float xs[8];
  xs[0] = bf2f((unsigned short)v[0]) - funkey(k0.x);
  xs[1] = bf2f((unsigned short)v[1]) - funkey(k0.y);
  xs[2] = bf2f((unsigned short)v[2]) - funkey(k0.z);
  xs[3] = bf2f((unsigned short)v[3]) - funkey(k0.w);
  xs[4] = bf2f((unsigned short)v[4]) - funkey(k1.x);
  xs[5] = bf2f((unsigned short)v[5]) - funkey(k1.y);
  xs[6] = bf2f((unsigned short)v[6]) - funkey(k1.z);
  xs[7] = bf2f((unsigned short)v[7]) - funkey(k1.w);
  float m = xs[0];
#pragma unroll
  for (int i = 1; i < 8; ++i) m = fmaxf(m, xs[i]);
  if ((q >> 3) == tid) sdiag = xs[q & 7];
  m = block_reduce_max256(m, sbuf);  // contains barriers -> sdiag visible
  float s = 0.f;
#pragma unroll
  for (int i = 0; i < 8; ++i) s += expf(xs[i] - m);
  s = block_reduce_sum256(s, sbuf);
  if (tid == 0) rowval[q] = sdiag - (m + logf(s));
}

// ---------------------------------------------------------------------------
// Kernel 4: loss = -mean_q rowval[q]  (single block)
__global__ __launch_bounds__(256) void final_loss(
    const float* __restrict__ rowval, float* __restrict__ out) {
  __shared__ float sbuf[4];
  const int tid = threadIdx.x;
  float s = 0.f;
#pragma unroll
  for (int i = 0; i < 8; ++i) s += rowval[tid + i * 256];
  s = block_reduce_sum256(s, sbuf);
  if (tid == 0) out[0] = -s * (1.0f / (float)BB);
}

// ---------------------------------------------------------------------------
extern "C" void kernel_launch(void* const* d_in, const int* in_sizes, int n_in,
                              void* d_out, int out_size, void* d_ws, size_t ws_size,
                              hipStream_t stream) {
  const float* qmean = (const float*)d_in[0];
  const float* qls   = (const float*)d_in[1];
  // d_in[2] query_z: cancels (broadcasts on target axis -> drops in colmax+softmax)
  const float* tmean = (const float*)d_in[3];
  const float* tls   = (const float*)d_in[4];
  // d_in[5] target_z: unused by reference
  const float* eps   = (const float*)d_in[6];

  char* ws = (char*)d_ws;
  unsigned short* Acat = (unsigned short*)(ws + 0);                  // 4 MB
  unsigned short* Bcat = (unsigned short*)(ws + (4u << 20));         // 4 MB
  float* qterm         = (float*)(ws + (8u << 20));                  // 8 KB
  unsigned* Mkey       = (unsigned*)(ws + (8u << 20) + 8192);        // 8 KB
  float* rowval        = (float*)(ws + (8u << 20) + 16384);          // 8 KB
  unsigned short* loc  = (unsigned short*)(ws + (8u << 20) + 65536); // 8 MB

  prep<<<2 * BB, 256, 0, stream>>>(qmean, qls, tmean, tls, eps,
                                   Acat, Bcat, qterm, Mkey);
  gemm_loc<<<dim3(BB / BN, BB / BM), 256, 0, stream>>>(Acat, Bcat, qterm, loc, Mkey);
  row_lse<<<BB, 256, 0, stream>>>(loc, Mkey, rowval);
  final_loss<<<1, 256, 0, stream>>>(rowval, (float*)d_out);
}

// Round 5
// 38.756 us; speedup vs baseline: 2.3391x; 1.0202x over previous
//
#include <hip/hip_runtime.h>
#include <math.h>

#define BB 2048
#define DD 512
#define NS 7
#define KK 1024   // 2*DD concatenated GEMM K
#define BM 128
#define BN 64
#define BK 64
#define NT (KK / BK)  // 16 K-steps

typedef __attribute__((ext_vector_type(8))) short short8;
typedef __attribute__((ext_vector_type(4))) float floatx4;

typedef const __attribute__((address_space(1))) void gv_t;
typedef __attribute__((address_space(3))) void lv_t;
__device__ __forceinline__ void gl2lds16(const void* g, void* l) {
  __builtin_amdgcn_global_load_lds((gv_t*)g, (lv_t*)l, 16, 0, 0);
}

__device__ __forceinline__ unsigned short f2bf(float f) {
  unsigned int u = __float_as_uint(f);
  u += 0x7FFFu + ((u >> 16) & 1u);  // RNE
  return (unsigned short)(u >> 16);
}
__device__ __forceinline__ float bf2f(unsigned short u) {
  return __uint_as_float(((unsigned)u) << 16);
}

// monotone float<->uint key for atomicMax over signed floats
__device__ __forceinline__ unsigned fkey(float f) {
  unsigned u = __float_as_uint(f);
  return (u & 0x80000000u) ? ~u : (u | 0x80000000u);
}
__device__ __forceinline__ float funkey(unsigned k) {
  unsigned u = (k & 0x80000000u) ? (k ^ 0x80000000u) : ~k;
  return __uint_as_float(u);
}

// chunk-XOR swizzle of the K index within each 64-col group, keyed by row&7.
// Producer (prep) writes swizzled; GEMM's linear global_load_lds staging then
// lands a swizzled LDS tile whose ds_read_b128 frag reads are bank-balanced.
__device__ __forceinline__ int swz(int row, int c) {
  return (c & ~0x38) | ((((c >> 3) ^ row) & 7) << 3);
}

__device__ __forceinline__ float wave_reduce_sum(float v) {
#pragma unroll
  for (int off = 32; off > 0; off >>= 1) v += __shfl_down(v, off, 64);
  return v;
}
__device__ __forceinline__ float wave_reduce_max(float v) {
#pragma unroll
  for (int off = 32; off > 0; off >>= 1) v = fmaxf(v, __shfl_down(v, off, 64));
  return v;
}
__device__ __forceinline__ float block_reduce_sum256(float v, float* sbuf) {
  v = wave_reduce_sum(v);
  if ((threadIdx.x & 63) == 0) sbuf[threadIdx.x >> 6] = v;
  __syncthreads();
  float r = sbuf[0] + sbuf[1] + sbuf[2] + sbuf[3];
  __syncthreads();
  return r;
}
__device__ __forceinline__ float block_reduce_max256(float v, float* sbuf) {
  v = wave_reduce_max(v);
  if ((threadIdx.x & 63) == 0) sbuf[threadIdx.x >> 6] = v;
  __syncthreads();
  float r = fmaxf(fmaxf(sbuf[0], sbuf[1]), fmaxf(sbuf[2], sbuf[3]));
  __syncthreads();
  return r;
}

// ---------------------------------------------------------------------------
// Kernel 1 (merged prep): blocks [0,2048) = query rows, [2048,4096) = targets.
// float2 loads (8B/lane) per G13.
__global__ __launch_bounds__(256) void prep(
    const float* __restrict__ qmean, const float* __restrict__ qls,
    const float* __restrict__ tmean, const float* __restrict__ tls,
    const float* __restrict__ eps,
    unsigned short* __restrict__ Acat, unsigned short* __restrict__ Bcat,
    float* __restrict__ qterm, unsigned* __restrict__ Mkey) {
  __shared__ float sbuf[4];
  const int b = blockIdx.x, tid = threadIdx.x;
  const int c0 = 2 * tid;
  if (b < BB) {
    const int q = b;
    float2 x = ((const float2*)(qmean + (size_t)q * DD))[tid];
    float2 l = ((const float2*)(qls + (size_t)q * DD))[tid];
    float ss = block_reduce_sum256(x.x * x.x + x.y * x.y, sbuf);
    float inv = 1.0f / fmaxf(sqrtf(ss), 1e-12f);
    float w0 = expf(-l.x), w1 = expf(-l.y);
    float n0 = x.x * inv, n1 = x.y * inv;
    unsigned short* arow = Acat + (size_t)q * KK;
    ushort2 wp, np;
    wp.x = f2bf(w0);             wp.y = f2bf(w1);
    np.x = f2bf(-2.0f * n0 * w0); np.y = f2bf(-2.0f * n1 * w1);
    *(ushort2*)&arow[swz(q, c0)]      = wp;
    *(ushort2*)&arow[swz(q, DD + c0)] = np;
    float qt = block_reduce_sum256(n0 * n0 * w0 + n1 * n1 * w1, sbuf);
    if (tid == 0) qterm[q] = qt;
  } else {
    const int t = b - BB;
    if (tid == 0) Mkey[t] = 0u;  // < fkey of any finite float
    float2 x = ((const float2*)(tmean + (size_t)t * DD))[tid];
    float2 l = ((const float2*)(tls + (size_t)t * DD))[tid];
    float ss = block_reduce_sum256(x.x * x.x + x.y * x.y, sbuf);
    float inv = 1.0f / fmaxf(sqrtf(ss), 1e-12f);
    float tm0 = x.x * inv, tm1 = x.y * inv;
    float sg0 = expf(l.x), sg1 = expf(l.y);
    float se0 = 0.f, sq0 = 0.f, se1 = 0.f, sq1 = 0.f;
    const float2* ep = (const float2*)(eps + (size_t)t * NS * DD);
#pragma unroll
    for (int s = 0; s < NS; ++s) {
      float2 e = ep[s * (DD / 2) + tid];
      se0 += e.x; sq0 += e.x * e.x;
      se1 += e.y; sq1 += e.y * e.y;
    }
    const float i7 = 1.0f / 7.0f;
    float m0 = sg0 * se0 * i7, m1 = sg1 * se1 * i7;
    unsigned short* brow = Bcat + (size_t)t * KK;
    ushort2 s2p, s1p;
    s2p.x = f2bf(tm0 * tm0 + 2.0f * tm0 * m0 + sg0 * sg0 * sq0 * i7);
    s2p.y = f2bf(tm1 * tm1 + 2.0f * tm1 * m1 + sg1 * sg1 * sq1 * i7);
    s1p.x = f2bf(tm0 + m0); s1p.y = f2bf(tm1 + m1);
    *(ushort2*)&brow[swz(t, c0)]      = s2p;
    *(ushort2*)&brow[swz(t, DD + c0)] = s1p;
  }
}

// ---------------------------------------------------------------------------
// Kernel 2: loc[q][t] = -0.5*(sum_k Acat[q,k]*Bcat[t,k] + qterm[q]) in bf16.
// 128x64 tile, grid 512 (2 blocks/CU), 4 waves. Triple-buffered LDS via
// global_load_lds dwordx4; raw s_barrier + counted vmcnt(6).
// 2-LEVEL XCD BLOCKING (round-5 change): each XCD owns an 8x8 tile rectangle
// (8 row-panels x 8 col-tiles): working set 2MB A + 1MB B < 4MB private L2,
// so the 192MB of tile re-reads become per-XCD L2 hits instead of LLC traffic.
__global__ __launch_bounds__(256) void gemm_loc(
    const unsigned short* __restrict__ Acat,
    const unsigned short* __restrict__ Bcat,
    const float* __restrict__ qterm,
    unsigned short* __restrict__ loc, unsigned* __restrict__ Mkey) {
  __shared__ short As[3][BM * BK];  // 3 x 16 KB
  __shared__ short Bs[3][BN * BK];  // 3 x  8 KB
  const int tid = threadIdx.x, lane = tid & 63, wid = tid >> 6;
  const int lin = blockIdx.y * (BB / BN) + blockIdx.x;  // hw dispatch id 0..511
  const int xcd = lin & 7, j = lin >> 3;                // dispatch round-robins XCDs
  const int tr = ((xcd >> 2) << 3) + (j >> 3);          // tile row 0..15
  const int tc = ((xcd & 3) << 3) + (j & 7);            // tile col 0..31
  const int brow = tr * BM, bcol = tc * BN;
  const int wr = wid >> 1, wc = wid & 1;          // wave 64x32 sub-tile
  const int fr = lane & 15, kg = lane >> 4, f7 = fr & 7;
  const int srow = lane >> 3, scol = (lane & 7) * 8;

  floatx4 acc[4][2];
#pragma unroll
  for (int m = 0; m < 4; ++m)
#pragma unroll
    for (int n = 0; n < 2; ++n) acc[m][n] = (floatx4){0.f, 0.f, 0.f, 0.f};

  const unsigned short* gA = Acat + (size_t)(brow + wid * 32 + srow) * KK + scol;
  const unsigned short* gB = Bcat + (size_t)(bcol + wid * 16 + srow) * KK + scol;

  // prologue: stage K-tiles 0,1 into buffers 0,1 (12 loads in flight / wave)
#pragma unroll
  for (int p = 0; p < 2; ++p) {
    short* la = &As[p][wid * 2048];
    short* lb = &Bs[p][wid * 1024];
#pragma unroll
    for (int j2 = 0; j2 < 4; ++j2) gl2lds16(gA + (size_t)j2 * 8 * KK + p * BK, la + j2 * 512);
#pragma unroll
    for (int j2 = 0; j2 < 2; ++j2) gl2lds16(gB + (size_t)j2 * 8 * KK + p * BK, lb + j2 * 512);
  }

#pragma unroll
  for (int kt = 0; kt < NT; ++kt) {
    // own tile-kt loads complete (vmcnt in-order); tile kt+1 may stay in flight
    if (kt < NT - 1) asm volatile("s_waitcnt vmcnt(6)" ::: "memory");
    else             asm volatile("s_waitcnt vmcnt(0)" ::: "memory");
    __builtin_amdgcn_s_barrier();  // all waves' tile-kt data now in LDS
    if (kt + 2 < NT) {
      // overwrite buf[(kt-1)%3]: all waves finished kt-1 reads before barrier
      const int kc = (kt + 2) * BK, nb = (kt + 2) % 3;
      short* la = &As[nb][wid * 2048];
      short* lb = &Bs[nb][wid * 1024];
#pragma unroll
      for (int j2 = 0; j2 < 4; ++j2) gl2lds16(gA + (size_t)j2 * 8 * KK + kc, la + j2 * 512);
#pragma unroll
      for (int j2 = 0; j2 < 2; ++j2) gl2lds16(gB + (size_t)j2 * 8 * KK + kc, lb + j2 * 512);
    }
    const short* a  = As[kt % 3];
    const short* bp = Bs[kt % 3];
#pragma unroll
    for (int kh = 0; kh < 2; ++kh) {
      const int co = (((kh * 4 + kg) ^ f7) << 3);  // un-swizzle chunk
      short8 af[4], bf[2];
#pragma unroll
      for (int m = 0; m < 4; ++m)
        af[m] = *reinterpret_cast<const short8*>(&a[(wr * 64 + m * 16 + fr) * BK + co]);
#pragma unroll
      for (int n = 0; n < 2; ++n)
        bf[n] = *reinterpret_cast<const short8*>(&bp[(wc * 32 + n * 16 + fr) * BK + co]);
#pragma unroll
      for (int m = 0; m < 4; ++m)
#pragma unroll
        for (int n = 0; n < 2; ++n)
          acc[m][n] = __builtin_amdgcn_mfma_f32_16x16x32_bf16(af[m], bf[n],
                                                              acc[m][n], 0, 0, 0);
    }
  }

  // epilogue: C row = 4*kg + r4 (+m*16 + wr*64), col = fr (+n*16 + wc*32)
#pragma unroll
  for (int n = 0; n < 2; ++n) {
    const int col = bcol + wc * 32 + n * 16 + fr;
    float cm = -3.402823466e38f;
#pragma unroll
    for (int m = 0; m < 4; ++m) {
      const int row = brow + wr * 64 + m * 16 + kg * 4;
#pragma unroll
      for (int r4 = 0; r4 < 4; ++r4) {
        float v = -0.5f * (acc[m][n][r4] + qterm[row + r4]);
        loc[(size_t)(row + r4) * BB + col] = f2bf(v);
        cm = fmaxf(cm, v);
      }
    }
    cm = fmaxf(cm, __shfl_xor(cm, 16, 64));
    cm = fmaxf(cm, __shfl_xor(cm, 32, 64));
    if (kg == 0) atomicMax(&Mkey[col], fkey(cm));  // order-invariant
  }
}

// ---------------------------------------------------------------------------
// Kernel 3: per-row LSE + diag -> rowval[q]. Single pass, all in registers;
// no global atomics (round-2 lesson: same-address atomics serialize).
__global__ __launch_bounds__(256) void row_lse(
    const unsigned short* __restrict__ loc, const unsigned* __restrict__ Mkey,
    float* __restrict__ rowval) {
  __shared__ float sbuf[4];
  __shared__ float sdiag;
  const int q = blockIdx.x, tid = threadIdx.x;
  short8 v = ((const short8*)(loc + (size_t)q * BB))[tid];  // t = 8tid..8tid+7
  uint4 k0 = ((const uint4*)Mkey)[2 * tid];
  uint4 k1 = ((const uint4*)Mkey)[2 * tid + 1];
  float xs[8];
  xs[0] = bf2f((unsigned short)v[0]) - funkey(k0.x);
  xs[1] = bf2f((unsigned short)v[1]) - funkey(k0.y);
  xs[2] = bf2f((unsigned short)v[2]) - funkey(k0.z);
  xs[3] = bf2f((unsigned short)v[3]) - funkey(k0.w);
  xs[4] = bf2f((unsigned short)v[4]) - funkey(k1.x);
  xs[5] = bf2f((unsigned short)v[5]) - funkey(k1.y);
  xs[6] = bf2f((unsigned short)v[6]) - funkey(k1.z);
  xs[7] = bf2f((unsigned short)v[7]) - funkey(k1.w);
  float m = xs[0];
#pragma unroll
  for (int i = 1; i < 8; ++i) m = fmaxf(m, xs[i]);
  if ((q >> 3) == tid) sdiag = xs[q & 7];
  m = block_reduce_max256(m, sbuf);  // contains barriers -> sdiag visible
  float s = 0.f;
#pragma unroll
  for (int i = 0; i < 8; ++i) s += expf(xs[i] - m);
  s = block_reduce_sum256(s, sbuf);
  if (tid == 0) rowval[q] = sdiag - (m + logf(s));
}

// ---------------------------------------------------------------------------
// Kernel 4: loss = -mean_q rowval[q]  (single block)
__global__ __launch_bounds__(256) void final_loss(
    const float* __restrict__ rowval, float* __restrict__ out) {
  __shared__ float sbuf[4];
  const int tid = threadIdx.x;
  float s = 0.f;
#pragma unroll
  for (int i = 0; i < 8; ++i) s += rowval[tid + i * 256];
  s = block_reduce_sum256(s, sbuf);
  if (tid == 0) out[0] = -s * (1.0f / (float)BB);
}

// ---------------------------------------------------------------------------
extern "C" void kernel_launch(void* const* d_in, const int* in_sizes, int n_in,
                              void* d_out, int out_size, void* d_ws, size_t ws_size,
                              hipStream_t stream) {
  const float* qmean = (const float*)d_in[0];
  const float* qls   = (const float*)d_in[1];
  // d_in[2] query_z: cancels (broadcasts on target axis -> drops in colmax+softmax)
  const float* tmean = (const float*)d_in[3];
  const float* tls   = (const float*)d_in[4];
  // d_in[5] target_z: unused by reference
  const float* eps   = (const float*)d_in[6];

  char* ws = (char*)d_ws;
  unsigned short* Acat = (unsigned short*)(ws + 0);                  // 4 MB
  unsigned short* Bcat = (unsigned short*)(ws + (4u << 20));         // 4 MB
  float* qterm         = (float*)(ws + (8u << 20));                  // 8 KB
  unsigned* Mkey       = (unsigned*)(ws + (8u << 20) + 8192);        // 8 KB
  float* rowval        = (float*)(ws + (8u << 20) + 16384);          // 8 KB
  unsigned short* loc  = (unsigned short*)(ws + (8u << 20) + 65536); // 8 MB

  prep<<<2 * BB, 256, 0, stream>>>(qmean, qls, tmean, tls, eps,
                                   Acat, Bcat, qterm, Mkey);
  gemm_loc<<<dim3(BB / BN, BB / BM), 256, 0, stream>>>(Acat, Bcat, qterm, loc, Mkey);
  row_lse<<<BB, 256, 0, stream>>>(loc, Mkey, rowval);
  final_loss<<<1, 256, 0, stream>>>(rowval, (float*)d_out);
}

// Round 6
// 36.190 us; speedup vs baseline: 2.5050x; 1.0709x over previous
//
#include <hip/hip_runtime.h>
#include <math.h>

#define BB 2048
#define DD 512
#define NS 7
#define KK 1024   // 2*DD concatenated GEMM K
#define BM 128
#define BN 64
#define BK 64
#define NT (KK / BK)  // 16 K-steps

typedef __attribute__((ext_vector_type(8))) short short8;
typedef __attribute__((ext_vector_type(4))) float floatx4;

typedef const __attribute__((address_space(1))) void gv_t;
typedef __attribute__((address_space(3))) void lv_t;
__device__ __forceinline__ void gl2lds16(const void* g, void* l) {
  __builtin_amdgcn_global_load_lds((gv_t*)g, (lv_t*)l, 16, 0, 0);
}

__device__ __forceinline__ unsigned short f2bf(float f) {
  unsigned int u = __float_as_uint(f);
  u += 0x7FFFu + ((u >> 16) & 1u);  // RNE
  return (unsigned short)(u >> 16);
}
__device__ __forceinline__ float bf2f(unsigned short u) {
  return __uint_as_float(((unsigned)u) << 16);
}

// monotone float<->uint key for atomicMax over signed floats
__device__ __forceinline__ unsigned fkey(float f) {
  unsigned u = __float_as_uint(f);
  return (u & 0x80000000u) ? ~u : (u | 0x80000000u);
}
__device__ __forceinline__ float funkey(unsigned k) {
  unsigned u = (k & 0x80000000u) ? (k ^ 0x80000000u) : ~k;
  return __uint_as_float(u);
}

// chunk-XOR swizzle of the K index within each 64-col group, keyed by row&7.
// Producer (prep) writes swizzled; GEMM's linear global_load_lds staging then
// lands a swizzled LDS tile whose ds_read_b128 frag reads are bank-balanced.
__device__ __forceinline__ int swz(int row, int c) {
  return (c & ~0x38) | ((((c >> 3) ^ row) & 7) << 3);
}

__device__ __forceinline__ float wave_reduce_sum(float v) {
#pragma unroll
  for (int off = 32; off > 0; off >>= 1) v += __shfl_down(v, off, 64);
  return v;
}
__device__ __forceinline__ float wave_reduce_max(float v) {
#pragma unroll
  for (int off = 32; off > 0; off >>= 1) v = fmaxf(v, __shfl_down(v, off, 64));
  return v;
}
__device__ __forceinline__ float block_reduce_sum256(float v, float* sbuf) {
  v = wave_reduce_sum(v);
  if ((threadIdx.x & 63) == 0) sbuf[threadIdx.x >> 6] = v;
  __syncthreads();
  float r = sbuf[0] + sbuf[1] + sbuf[2] + sbuf[3];
  __syncthreads();
  return r;
}
__device__ __forceinline__ float block_reduce_max256(float v, float* sbuf) {
  v = wave_reduce_max(v);
  if ((threadIdx.x & 63) == 0) sbuf[threadIdx.x >> 6] = v;
  __syncthreads();
  float r = fmaxf(fmaxf(sbuf[0], sbuf[1]), fmaxf(sbuf[2], sbuf[3]));
  __syncthreads();
  return r;
}

// ---------------------------------------------------------------------------
// Kernel 1 (merged prep, round-6: 16B/lane float4, 2 rows per block).
// Blocks [0,1024): query rows 2b,2b+1.  Blocks [1024,2048): target rows.
// Group g = tid>>7 owns one row with 128 threads (2 waves).
__global__ __launch_bounds__(256) void prep(
    const float* __restrict__ qmean, const float* __restrict__ qls,
    const float* __restrict__ tmean, const float* __restrict__ tls,
    const float* __restrict__ eps,
    unsigned short* __restrict__ Acat, unsigned short* __restrict__ Bcat,
    float* __restrict__ qterm, unsigned* __restrict__ Mkey) {
  __shared__ float sbuf[8];  // [0..3]: reduce round 0, [4..7]: round 1
  const int b = blockIdx.x, tid = threadIdx.x;
  const int g = tid >> 7, lid = tid & 127, wv = (tid >> 6) & 1;
  const int c0 = 4 * lid;
  if (b < BB / 2) {
    const int q = 2 * b + g;
    float4 x = ((const float4*)(qmean + (size_t)q * DD))[lid];
    float4 l = ((const float4*)(qls + (size_t)q * DD))[lid];
    float ss = x.x * x.x + x.y * x.y + x.z * x.z + x.w * x.w;
    ss = wave_reduce_sum(ss);
    if ((tid & 63) == 0) sbuf[(g << 1) | wv] = ss;
    __syncthreads();
    ss = sbuf[g << 1] + sbuf[(g << 1) | 1];
    float inv = 1.0f / fmaxf(sqrtf(ss), 1e-12f);
    float w0 = expf(-l.x), w1 = expf(-l.y), w2 = expf(-l.z), w3 = expf(-l.w);
    float n0 = x.x * inv, n1 = x.y * inv, n2 = x.z * inv, n3 = x.w * inv;
    unsigned short* arow = Acat + (size_t)q * KK;
    ushort4 wp, np;
    wp.x = f2bf(w0); wp.y = f2bf(w1); wp.z = f2bf(w2); wp.w = f2bf(w3);
    np.x = f2bf(-2.0f * n0 * w0); np.y = f2bf(-2.0f * n1 * w1);
    np.z = f2bf(-2.0f * n2 * w2); np.w = f2bf(-2.0f * n3 * w3);
    *(ushort4*)&arow[swz(q, c0)]      = wp;
    *(ushort4*)&arow[swz(q, DD + c0)] = np;
    float qt = n0 * n0 * w0 + n1 * n1 * w1 + n2 * n2 * w2 + n3 * n3 * w3;
    qt = wave_reduce_sum(qt);
    if ((tid & 63) == 0) sbuf[4 + ((g << 1) | wv)] = qt;
    __syncthreads();
    if (lid == 0) qterm[q] = sbuf[4 + (g << 1)] + sbuf[4 + ((g << 1) | 1)];
  } else {
    const int t = 2 * (b - BB / 2) + g;
    if (lid == 0) Mkey[t] = 0u;  // < fkey of any finite float
    float4 x = ((const float4*)(tmean + (size_t)t * DD))[lid];
    float4 l = ((const float4*)(tls + (size_t)t * DD))[lid];
    float ss = x.x * x.x + x.y * x.y + x.z * x.z + x.w * x.w;
    ss = wave_reduce_sum(ss);
    if ((tid & 63) == 0) sbuf[(g << 1) | wv] = ss;
    __syncthreads();
    ss = sbuf[g << 1] + sbuf[(g << 1) | 1];
    float inv = 1.0f / fmaxf(sqrtf(ss), 1e-12f);
    float tm0 = x.x * inv, tm1 = x.y * inv, tm2 = x.z * inv, tm3 = x.w * inv;
    float sg0 = expf(l.x), sg1 = expf(l.y), sg2 = expf(l.z), sg3 = expf(l.w);
    float se0 = 0.f, se1 = 0.f, se2 = 0.f, se3 = 0.f;
    float sq0 = 0.f, sq1 = 0.f, sq2 = 0.f, sq3 = 0.f;
    const float4* ep = (const float4*)(eps + (size_t)t * NS * DD);
#pragma unroll
    for (int s = 0; s < NS; ++s) {
      float4 e = ep[s * (DD / 4) + lid];
      se0 += e.x; sq0 += e.x * e.x;
      se1 += e.y; sq1 += e.y * e.y;
      se2 += e.z; sq2 += e.z * e.z;
      se3 += e.w; sq3 += e.w * e.w;
    }
    const float i7 = 1.0f / 7.0f;
    float m0 = sg0 * se0 * i7, m1 = sg1 * se1 * i7;
    float m2 = sg2 * se2 * i7, m3 = sg3 * se3 * i7;
    unsigned short* brow = Bcat + (size_t)t * KK;
    ushort4 s2p, s1p;
    s2p.x = f2bf(tm0 * tm0 + 2.0f * tm0 * m0 + sg0 * sg0 * sq0 * i7);
    s2p.y = f2bf(tm1 * tm1 + 2.0f * tm1 * m1 + sg1 * sg1 * sq1 * i7);
    s2p.z = f2bf(tm2 * tm2 + 2.0f * tm2 * m2 + sg2 * sg2 * sq2 * i7);
    s2p.w = f2bf(tm3 * tm3 + 2.0f * tm3 * m3 + sg3 * sg3 * sq3 * i7);
    s1p.x = f2bf(tm0 + m0); s1p.y = f2bf(tm1 + m1);
    s1p.z = f2bf(tm2 + m2); s1p.w = f2bf(tm3 + m3);
    *(ushort4*)&brow[swz(t, c0)]      = s2p;
    *(ushort4*)&brow[swz(t, DD + c0)] = s1p;
  }
}

// ---------------------------------------------------------------------------
// Kernel 2: loc[q][t] = -0.5*(sum_k Acat[q,k]*Bcat[t,k] + qterm[q]) in bf16.
// 128x64 tile, grid 512 (2 blocks/CU), 4 waves. Triple-buffered LDS via
// global_load_lds dwordx4; raw s_barrier + counted vmcnt(6); 2-level XCD
// blocking. Round-6: s_setprio(1) around each MFMA cluster (T5).
__global__ __launch_bounds__(256) void gemm_loc(
    const unsigned short* __restrict__ Acat,
    const unsigned short* __restrict__ Bcat,
    const float* __restrict__ qterm,
    unsigned short* __restrict__ loc, unsigned* __restrict__ Mkey) {
  __shared__ short As[3][BM * BK];  // 3 x 16 KB
  __shared__ short Bs[3][BN * BK];  // 3 x  8 KB
  const int tid = threadIdx.x, lane = tid & 63, wid = tid >> 6;
  const int lin = blockIdx.y * (BB / BN) + blockIdx.x;  // hw dispatch id 0..511
  const int xcd = lin & 7, j = lin >> 3;                // dispatch round-robins XCDs
  const int tr = ((xcd >> 2) << 3) + (j >> 3);          // tile row 0..15
  const int tc = ((xcd & 3) << 3) + (j & 7);            // tile col 0..31
  const int brow = tr * BM, bcol = tc * BN;
  const int wr = wid >> 1, wc = wid & 1;          // wave 64x32 sub-tile
  const int fr = lane & 15, kg = lane >> 4, f7 = fr & 7;
  const int srow = lane >> 3, scol = (lane & 7) * 8;

  floatx4 acc[4][2];
#pragma unroll
  for (int m = 0; m < 4; ++m)
#pragma unroll
    for (int n = 0; n < 2; ++n) acc[m][n] = (floatx4){0.f, 0.f, 0.f, 0.f};

  const unsigned short* gA = Acat + (size_t)(brow + wid * 32 + srow) * KK + scol;
  const unsigned short* gB = Bcat + (size_t)(bcol + wid * 16 + srow) * KK + scol;

  // prologue: stage K-tiles 0,1 into buffers 0,1 (12 loads in flight / wave)
#pragma unroll
  for (int p = 0; p < 2; ++p) {
    short* la = &As[p][wid * 2048];
    short* lb = &Bs[p][wid * 1024];
#pragma unroll
    for (int j2 = 0; j2 < 4; ++j2) gl2lds16(gA + (size_t)j2 * 8 * KK + p * BK, la + j2 * 512);
#pragma unroll
    for (int j2 = 0; j2 < 2; ++j2) gl2lds16(gB + (size_t)j2 * 8 * KK + p * BK, lb + j2 * 512);
  }

#pragma unroll
  for (int kt = 0; kt < NT; ++kt) {
    // own tile-kt loads complete (vmcnt in-order); tile kt+1 may stay in flight
    if (kt < NT - 1) asm volatile("s_waitcnt vmcnt(6)" ::: "memory");
    else             asm volatile("s_waitcnt vmcnt(0)" ::: "memory");
    __builtin_amdgcn_s_barrier();  // all waves' tile-kt data now in LDS
    if (kt + 2 < NT) {
      // overwrite buf[(kt-1)%3]: all waves finished kt-1 reads before barrier
      const int kc = (kt + 2) * BK, nb = (kt + 2) % 3;
      short* la = &As[nb][wid * 2048];
      short* lb = &Bs[nb][wid * 1024];
#pragma unroll
      for (int j2 = 0; j2 < 4; ++j2) gl2lds16(gA + (size_t)j2 * 8 * KK + kc, la + j2 * 512);
#pragma unroll
      for (int j2 = 0; j2 < 2; ++j2) gl2lds16(gB + (size_t)j2 * 8 * KK + kc, lb + j2 * 512);
    }
    const short* a  = As[kt % 3];
    const short* bp = Bs[kt % 3];
#pragma unroll
    for (int kh = 0; kh < 2; ++kh) {
      const int co = (((kh * 4 + kg) ^ f7) << 3);  // un-swizzle chunk
      short8 af[4], bf[2];
#pragma unroll
      for (int m = 0; m < 4; ++m)
        af[m] = *reinterpret_cast<const short8*>(&a[(wr * 64 + m * 16 + fr) * BK + co]);
#pragma unroll
      for (int n = 0; n < 2; ++n)
        bf[n] = *reinterpret_cast<const short8*>(&bp[(wc * 32 + n * 16 + fr) * BK + co]);
      __builtin_amdgcn_s_setprio(1);
#pragma unroll
      for (int m = 0; m < 4; ++m)
#pragma unroll
        for (int n = 0; n < 2; ++n)
          acc[m][n] = __builtin_amdgcn_mfma_f32_16x16x32_bf16(af[m], bf[n],
                                                              acc[m][n], 0, 0, 0);
      __builtin_amdgcn_s_setprio(0);
    }
  }

  // epilogue: C row = 4*kg + r4 (+m*16 + wr*64), col = fr (+n*16 + wc*32)
#pragma unroll
  for (int n = 0; n < 2; ++n) {
    const int col = bcol + wc * 32 + n * 16 + fr;
    float cm = -3.402823466e38f;
#pragma unroll
    for (int m = 0; m < 4; ++m) {
      const int row = brow + wr * 64 + m * 16 + kg * 4;
#pragma unroll
      for (int r4 = 0; r4 < 4; ++r4) {
        float v = -0.5f * (acc[m][n][r4] + qterm[row + r4]);
        loc[(size_t)(row + r4) * BB + col] = f2bf(v);
        cm = fmaxf(cm, v);
      }
    }
    cm = fmaxf(cm, __shfl_xor(cm, 16, 64));
    cm = fmaxf(cm, __shfl_xor(cm, 32, 64));
    if (kg == 0) atomicMax(&Mkey[col], fkey(cm));  // order-invariant
  }
}

// ---------------------------------------------------------------------------
// Kernel 3: per-row LSE + diag -> rowval[q]. Single pass, all in registers;
// no global atomics (round-2 lesson: same-address atomics serialize brutally).
__global__ __launch_bounds__(256) void row_lse(
    const unsigned short* __restrict__ loc, const unsigned* __restrict__ Mkey,
    float* __restrict__ rowval) {
  __shared__ float sbuf[4];
  __shared__ float sdiag;
  const int q = blockIdx.x, tid = threadIdx.x;
  short8 v = ((const short8*)(loc + (size_t)q * BB))[tid];  // t = 8tid..8tid+7
  uint4 k0 = ((const uint4*)Mkey)[2 * tid];
  uint4 k1 = ((const uint4*)Mkey)[2 * tid + 1];
  float xs[8];
  xs[0] = bf2f((unsigned short)v[0]) - funkey(k0.x);
  xs[1] = bf2f((unsigned short)v[1]) - funkey(k0.y);
  xs[2] = bf2f((unsigned short)v[2]) - funkey(k0.z);
  xs[3] = bf2f((unsigned short)v[3]) - funkey(k0.w);
  xs[4] = bf2f((unsigned short)v[4]) - funkey(k1.x);
  xs[5] = bf2f((unsigned short)v[5]) - funkey(k1.y);
  xs[6] = bf2f((unsigned short)v[6]) - funkey(k1.z);
  xs[7] = bf2f((unsigned short)v[7]) - funkey(k1.w);
  float m = xs[0];
#pragma unroll
  for (int i = 1; i < 8; ++i) m = fmaxf(m, xs[i]);
  if ((q >> 3) == tid) sdiag = xs[q & 7];
  m = block_reduce_max256(m, sbuf);  // contains barriers -> sdiag visible
  float s = 0.f;
#pragma unroll
  for (int i = 0; i < 8; ++i) s += expf(xs[i] - m);
  s = block_reduce_sum256(s, sbuf);
  if (tid == 0) rowval[q] = sdiag - (m + logf(s));
}

// ---------------------------------------------------------------------------
// Kernel 4: loss = -mean_q rowval[q]  (single block)
__global__ __launch_bounds__(256) void final_loss(
    const float* __restrict__ rowval, float* __restrict__ out) {
  __shared__ float sbuf[4];
  const int tid = threadIdx.x;
  float s = 0.f;
#pragma unroll
  for (int i = 0; i < 8; ++i) s += rowval[tid + i * 256];
  s = block_reduce_sum256(s, sbuf);
  if (tid == 0) out[0] = -s * (1.0f / (float)BB);
}

// ---------------------------------------------------------------------------
extern "C" void kernel_launch(void* const* d_in, const int* in_sizes, int n_in,
                              void* d_out, int out_size, void* d_ws, size_t ws_size,
                              hipStream_t stream) {
  const float* qmean = (const float*)d_in[0];
  const float* qls   = (const float*)d_in[1];
  // d_in[2] query_z: cancels (broadcasts on target axis -> drops in colmax+softmax)
  const float* tmean = (const float*)d_in[3];
  const float* tls   = (const float*)d_in[4];
  // d_in[5] target_z: unused by reference
  const float* eps   = (const float*)d_in[6];

  char* ws = (char*)d_ws;
  unsigned short* Acat = (unsigned short*)(ws + 0);                  // 4 MB
  unsigned short* Bcat = (unsigned short*)(ws + (4u << 20));         // 4 MB
  float* qterm         = (float*)(ws + (8u << 20));                  // 8 KB
  unsigned* Mkey       = (unsigned*)(ws + (8u << 20) + 8192);        // 8 KB
  float* rowval        = (float*)(ws + (8u << 20) + 16384);          // 8 KB
  unsigned short* loc  = (unsigned short*)(ws + (8u << 20) + 65536); // 8 MB

  prep<<<BB, 256, 0, stream>>>(qmean, qls, tmean, tls, eps,
                               Acat, Bcat, qterm, Mkey);
  gemm_loc<<<dim3(BB / BN, BB / BM), 256, 0, stream>>>(Acat, Bcat, qterm, loc, Mkey);
  row_lse<<<BB, 256, 0, stream>>>(loc, Mkey, rowval);
  final_loss<<<1, 256, 0, stream>>>(rowval, (float*)d_out);
}